// Round 14
// baseline (64.542 us; speedup 1.0000x reference)
//
#include <hip/hip_runtime.h>

// ContinuityLoss: loss = 0.01/(n(n-1)) * sum_{i!=j} exp(-|pi-pj|^2/2) * |oi-oj|
// points: [N,2] f32, outputs: [N,8] f32, scalar f32 out. N = 8192.
//
// R13: R12's verified norm-augmented MFMA math (16x16x16 f16, absmax 0.0),
// repackaged for latency tolerance. R12 used 8256 one-wave workgroups: the
// ~16 WG/CU slot cap limited residency to ~4 waves/SIMD and each wave's
// critical path (prologue loads + per-jt loads + MFMA->VALU deps + serial
// acc chain) was exposed -> ~7k cyc/wave vs ~1.8k issue-sum.
// Changes (packaging only, math identical):
//  - 4 waves per 256-thread block -> 2064 blocks; WG cap no longer binds
//    (up to 8 waves/SIMD). Adjacent tiles share i-rows -> L1 reuse.
//  - explicit prefetch of jt+1's j-side loads before jt's MFMA+epilogue
//  - 4 independent accumulators (per-e) break the serial fmaf chain
//  - block-level partial (4-wave LDS reduce) -> 2064 doubles, coalesced final
// Math recap:  A_O=[o_i,|o_i|^2,1,0..], B_O=[-2o_j,1,|o_j|^2,0..] (K=10<=16)
//   -> mfma emits |oi-oj|^2 complete; A_P=[p_i,KE*pn_i,1,0], B_P=[M2*p_j,1,
//   KE*pn_j,0] -> mfma emits finished exp2 arg. Epilogue: fmax,sqrt,exp2,fma.
// Triangular tile grid (128x128 tiles of 64x64), diag tiles mask j>i; x2 in
// the final scale.

typedef float v2f __attribute__((ext_vector_type(2)));
typedef float v4f __attribute__((ext_vector_type(4)));
typedef _Float16 h4 __attribute__((ext_vector_type(4)));
typedef float f32x4 __attribute__((ext_vector_type(4)));

constexpr int N_PTS  = 8192;
constexpr int TDIM   = N_PTS / 64;                // 128 tiles per side
constexpr int NTILES = TDIM * (TDIM + 1) / 2;     // 8256
constexpr int WPB    = 4;                         // waves per block
constexpr int NBLOCKS = NTILES / WPB;             // 2064

constexpr float KE = -0.72134752044448169f;  // -0.5*log2(e)
constexpr float M2 =  1.4426950408889634f;   // -2*KE = log2(e)

__device__ __forceinline__ int tri_before(int r) {
    return r * TDIM - (r * (r - 1)) / 2;
}

__global__ __launch_bounds__(256, 6) void cont_pairs(
    const float* __restrict__ points, const float* __restrict__ outputs,
    double* __restrict__ partials)
{
    const int tid  = threadIdx.x;
    const int wid  = tid >> 6;
    const int lane = tid & 63;
    const int g    = blockIdx.x * WPB + wid;     // global tile id, 0..8255

    // closed-form upper-tri decode + exact integer fixup
    int ti = (int)((2 * TDIM + 1 -
                    sqrtf((float)((2 * TDIM + 1) * (2 * TDIM + 1) - 8 * g))) * 0.5f);
    ti = ti < 0 ? 0 : (ti > TDIM - 1 ? TDIM - 1 : ti);
    while (tri_before(ti + 1) <= g) ++ti;
    while (tri_before(ti) > g) --ti;
    const int tj = ti + (g - tri_before(ti));
    const bool diag = (ti == tj);

    const int q = lane >> 4, cl = lane & 15;
    const int rowbase = ti * 64, colbase = tj * 64;

    const _Float16 h0 = (_Float16)0.f, h1 = (_Float16)1.f;

    // i-side fragments (A operands), norm-augmented
    h4 aO[4], aP[4];
    #pragma unroll
    for (int it = 0; it < 4; ++it) {
        const int i = rowbase + it * 16 + cl;
        const v4f* o = reinterpret_cast<const v4f*>(outputs + 8 * i);
        const v4f x = o[0], y = o[1];
        const v4f s = x * x + y * y;
        const float on = (s.x + s.y) + (s.z + s.w);
        const v2f p = reinterpret_cast<const v2f*>(points)[i];
        const float pn = p.x * p.x + p.y * p.y;
        h4 a;
        if (q == 0)      a = h4{(_Float16)x.x, (_Float16)x.y, (_Float16)x.z, (_Float16)x.w};
        else if (q == 1) a = h4{(_Float16)y.x, (_Float16)y.y, (_Float16)y.z, (_Float16)y.w};
        else if (q == 2) a = h4{(_Float16)on, h1, h0, h0};
        else             a = h4{h0, h0, h0, h0};
        aO[it] = a;
        if (q == 0) aP[it] = h4{(_Float16)p.x, (_Float16)p.y, (_Float16)(KE * pn), h1};
        else        aP[it] = h4{h0, h0, h0, h0};
    }

    float accE[4] = {0.f, 0.f, 0.f, 0.f};

    // prefetched j-side raw data for jt=0
    v4f jx, jy; v2f jp;
    {
        const int j = colbase + cl;
        const v4f* o = reinterpret_cast<const v4f*>(outputs + 8 * j);
        jx = o[0]; jy = o[1];
        jp = reinterpret_cast<const v2f*>(points)[j];
    }

    #pragma unroll
    for (int jt = 0; jt < 4; ++jt) {
        // build B fragments from prefetched data
        const v4f s = jx * jx + jy * jy;
        const float on = (s.x + s.y) + (s.z + s.w);
        const float pn = jp.x * jp.x + jp.y * jp.y;
        h4 bO, bP;
        if (q == 0)      bO = h4{(_Float16)(-2.f * jx.x), (_Float16)(-2.f * jx.y),
                                 (_Float16)(-2.f * jx.z), (_Float16)(-2.f * jx.w)};
        else if (q == 1) bO = h4{(_Float16)(-2.f * jy.x), (_Float16)(-2.f * jy.y),
                                 (_Float16)(-2.f * jy.z), (_Float16)(-2.f * jy.w)};
        else if (q == 2) bO = h4{h1, (_Float16)on, h0, h0};
        else             bO = h4{h0, h0, h0, h0};
        if (q == 0) bP = h4{(_Float16)(M2 * jp.x), (_Float16)(M2 * jp.y), h1,
                            (_Float16)(KE * pn)};
        else        bP = h4{h0, h0, h0, h0};
        const int jcol = jt * 16 + cl;           // C/D col of this lane

        // prefetch next jt's raw data before compute
        if (jt < 3) {
            const int jn = colbase + (jt + 1) * 16 + cl;
            const v4f* o = reinterpret_cast<const v4f*>(outputs + 8 * jn);
            jx = o[0]; jy = o[1];
            jp = reinterpret_cast<const v2f*>(points)[jn];
        }

        #pragma unroll
        for (int it = 0; it < 4; ++it) {
            const f32x4 z = {0.f, 0.f, 0.f, 0.f};
            f32x4 dO = __builtin_amdgcn_mfma_f32_16x16x16f16(aO[it], bO, z, 0, 0, 0);
            f32x4 dP = __builtin_amdgcn_mfma_f32_16x16x16f16(aP[it], bP, z, 0, 0, 0);
            #pragma unroll
            for (int e = 0; e < 4; ++e) {
                float diff = __builtin_amdgcn_sqrtf(fmaxf(dO[e], 0.f));
                if (diag) {
                    const int irow = it * 16 + q * 4 + e;   // C/D row
                    diff = (jcol > irow) ? diff : 0.f;
                }
                accE[e] = fmaf(__builtin_amdgcn_exp2f(dP[e]), diff, accE[e]);
            }
        }
    }

    float accS = (accE[0] + accE[1]) + (accE[2] + accE[3]);
    #pragma unroll
    for (int off = 32; off > 0; off >>= 1)
        accS += __shfl_down(accS, off, 64);

    __shared__ float wpart[WPB];
    if (lane == 0) wpart[wid] = accS;
    __syncthreads();
    if (tid == 0) {
        double d = 0.0;
        #pragma unroll
        for (int w = 0; w < WPB; ++w) d += (double)wpart[w];
        partials[blockIdx.x] = d;
    }
}

__global__ __launch_bounds__(256) void cont_final(
    const double* __restrict__ partials, int nparts,
    float* __restrict__ out, double scale)
{
    const int tid = threadIdx.x;
    double sum = 0.0;
    for (int i = tid; i < nparts; i += 256) sum += partials[i];
    #pragma unroll
    for (int off = 32; off > 0; off >>= 1)
        sum += __shfl_down(sum, off, 64);

    __shared__ double ws[256 / 64];
    if ((tid & 63) == 0) ws[tid >> 6] = sum;
    __syncthreads();
    if (tid == 0) {
        double t = 0.0;
        #pragma unroll
        for (int w = 0; w < 256 / 64; ++w) t += ws[w];
        out[0] = (float)(t * scale);
    }
}

extern "C" void kernel_launch(void* const* d_in, const int* in_sizes, int n_in,
                              void* d_out, int out_size, void* d_ws, size_t ws_size,
                              hipStream_t stream) {
    const float* points  = (const float*)d_in[0];
    const float* outputs = (const float*)d_in[1];
    float* out = (float*)d_out;

    const int n = in_sizes[0] / 2;             // 8192
    double* partials = (double*)d_ws;          // 2064 * 8B = 16.5 KB scratch

    cont_pairs<<<dim3(NBLOCKS), dim3(256), 0, stream>>>(points, outputs, partials);

    // each unordered pair counted once -> weight 2 folded into the scale
    const double scale = 0.01 * 2.0 / ((double)n * (double)(n - 1));
    cont_final<<<1, 256, 0, stream>>>(partials, NBLOCKS, out, scale);
}

// Round 15
// 26.404 us; speedup vs baseline: 2.4444x; 2.4444x over previous
//
#include <hip/hip_runtime.h>

// ContinuityLoss: loss = 0.01/(n(n-1)) * sum_{i!=j} exp(-|pi-pj|^2/2) * |oi-oj|
// points: [N,2] f32, outputs: [N,8] f32, scalar f32 out. N = 8192.
//
// R14 = R13 with the register cap fixed. R13's __launch_bounds__(256,6)
// forced VGPR=40 -> fragment state spilled to scratch -> 200 MB of HBM
// round-trips (FETCH 78 MB / WRITE 120 MB measured) -> memory-bound at 64us.
// Change: __launch_bounds__(256,4) (VGPR cap 128; kernel needs ~60; HW can
// still reach 8 waves/SIMD via VGPR count). Everything else identical:
//  - norm-augmented MFMA (verified absmax 0.0 since R12):
//      A_O=[o_i,|o_i|^2,1,0..], B_O=[-2o_j,1,|o_j|^2,0..] -> dd complete
//      A_P=[p_i,KE*pn_i,1,0],  B_P=[M2*p_j,1,KE*pn_j,0]  -> exp2 arg
//    epilogue: fmax,sqrt,exp2,fma per pair.
//  - 4 waves/block (2064 blocks), tiles consecutive -> i-row L1 reuse
//  - j-side prefetch, 4 split accumulators, 4-wave LDS block reduce
//  - triangular tile grid, diag tiles mask j>i, x2 in final scale

typedef float v2f __attribute__((ext_vector_type(2)));
typedef float v4f __attribute__((ext_vector_type(4)));
typedef _Float16 h4 __attribute__((ext_vector_type(4)));
typedef float f32x4 __attribute__((ext_vector_type(4)));

constexpr int N_PTS  = 8192;
constexpr int TDIM   = N_PTS / 64;                // 128 tiles per side
constexpr int NTILES = TDIM * (TDIM + 1) / 2;     // 8256
constexpr int WPB    = 4;                         // waves per block
constexpr int NBLOCKS = NTILES / WPB;             // 2064

constexpr float KE = -0.72134752044448169f;  // -0.5*log2(e)
constexpr float M2 =  1.4426950408889634f;   // -2*KE = log2(e)

__device__ __forceinline__ int tri_before(int r) {
    return r * TDIM - (r * (r - 1)) / 2;
}

__global__ __launch_bounds__(256, 4) void cont_pairs(
    const float* __restrict__ points, const float* __restrict__ outputs,
    double* __restrict__ partials)
{
    const int tid  = threadIdx.x;
    const int wid  = tid >> 6;
    const int lane = tid & 63;
    const int g    = blockIdx.x * WPB + wid;     // global tile id, 0..8255

    // closed-form upper-tri decode + exact integer fixup
    int ti = (int)((2 * TDIM + 1 -
                    sqrtf((float)((2 * TDIM + 1) * (2 * TDIM + 1) - 8 * g))) * 0.5f);
    ti = ti < 0 ? 0 : (ti > TDIM - 1 ? TDIM - 1 : ti);
    while (tri_before(ti + 1) <= g) ++ti;
    while (tri_before(ti) > g) --ti;
    const int tj = ti + (g - tri_before(ti));
    const bool diag = (ti == tj);

    const int q = lane >> 4, cl = lane & 15;
    const int rowbase = ti * 64, colbase = tj * 64;

    const _Float16 h0 = (_Float16)0.f, h1 = (_Float16)1.f;

    // i-side fragments (A operands), norm-augmented
    h4 aO[4], aP[4];
    #pragma unroll
    for (int it = 0; it < 4; ++it) {
        const int i = rowbase + it * 16 + cl;
        const v4f* o = reinterpret_cast<const v4f*>(outputs + 8 * i);
        const v4f x = o[0], y = o[1];
        const v4f s = x * x + y * y;
        const float on = (s.x + s.y) + (s.z + s.w);
        const v2f p = reinterpret_cast<const v2f*>(points)[i];
        const float pn = p.x * p.x + p.y * p.y;
        h4 a;
        if (q == 0)      a = h4{(_Float16)x.x, (_Float16)x.y, (_Float16)x.z, (_Float16)x.w};
        else if (q == 1) a = h4{(_Float16)y.x, (_Float16)y.y, (_Float16)y.z, (_Float16)y.w};
        else if (q == 2) a = h4{(_Float16)on, h1, h0, h0};
        else             a = h4{h0, h0, h0, h0};
        aO[it] = a;
        if (q == 0) aP[it] = h4{(_Float16)p.x, (_Float16)p.y, (_Float16)(KE * pn), h1};
        else        aP[it] = h4{h0, h0, h0, h0};
    }

    float accE[4] = {0.f, 0.f, 0.f, 0.f};

    // prefetched j-side raw data for jt=0
    v4f jx, jy; v2f jp;
    {
        const int j = colbase + cl;
        const v4f* o = reinterpret_cast<const v4f*>(outputs + 8 * j);
        jx = o[0]; jy = o[1];
        jp = reinterpret_cast<const v2f*>(points)[j];
    }

    #pragma unroll
    for (int jt = 0; jt < 4; ++jt) {
        // build B fragments from prefetched data
        const v4f s = jx * jx + jy * jy;
        const float on = (s.x + s.y) + (s.z + s.w);
        const float pn = jp.x * jp.x + jp.y * jp.y;
        h4 bO, bP;
        if (q == 0)      bO = h4{(_Float16)(-2.f * jx.x), (_Float16)(-2.f * jx.y),
                                 (_Float16)(-2.f * jx.z), (_Float16)(-2.f * jx.w)};
        else if (q == 1) bO = h4{(_Float16)(-2.f * jy.x), (_Float16)(-2.f * jy.y),
                                 (_Float16)(-2.f * jy.z), (_Float16)(-2.f * jy.w)};
        else if (q == 2) bO = h4{h1, (_Float16)on, h0, h0};
        else             bO = h4{h0, h0, h0, h0};
        if (q == 0) bP = h4{(_Float16)(M2 * jp.x), (_Float16)(M2 * jp.y), h1,
                            (_Float16)(KE * pn)};
        else        bP = h4{h0, h0, h0, h0};
        const int jcol = jt * 16 + cl;           // C/D col of this lane

        // prefetch next jt's raw data before compute
        if (jt < 3) {
            const int jn = colbase + (jt + 1) * 16 + cl;
            const v4f* o = reinterpret_cast<const v4f*>(outputs + 8 * jn);
            jx = o[0]; jy = o[1];
            jp = reinterpret_cast<const v2f*>(points)[jn];
        }

        #pragma unroll
        for (int it = 0; it < 4; ++it) {
            const f32x4 z = {0.f, 0.f, 0.f, 0.f};
            f32x4 dO = __builtin_amdgcn_mfma_f32_16x16x16f16(aO[it], bO, z, 0, 0, 0);
            f32x4 dP = __builtin_amdgcn_mfma_f32_16x16x16f16(aP[it], bP, z, 0, 0, 0);
            #pragma unroll
            for (int e = 0; e < 4; ++e) {
                float diff = __builtin_amdgcn_sqrtf(fmaxf(dO[e], 0.f));
                if (diag) {
                    const int irow = it * 16 + q * 4 + e;   // C/D row
                    diff = (jcol > irow) ? diff : 0.f;
                }
                accE[e] = fmaf(__builtin_amdgcn_exp2f(dP[e]), diff, accE[e]);
            }
        }
    }

    float accS = (accE[0] + accE[1]) + (accE[2] + accE[3]);
    #pragma unroll
    for (int off = 32; off > 0; off >>= 1)
        accS += __shfl_down(accS, off, 64);

    __shared__ float wpart[WPB];
    if (lane == 0) wpart[wid] = accS;
    __syncthreads();
    if (tid == 0) {
        double d = 0.0;
        #pragma unroll
        for (int w = 0; w < WPB; ++w) d += (double)wpart[w];
        partials[blockIdx.x] = d;
    }
}

__global__ __launch_bounds__(256) void cont_final(
    const double* __restrict__ partials, int nparts,
    float* __restrict__ out, double scale)
{
    const int tid = threadIdx.x;
    double sum = 0.0;
    for (int i = tid; i < nparts; i += 256) sum += partials[i];
    #pragma unroll
    for (int off = 32; off > 0; off >>= 1)
        sum += __shfl_down(sum, off, 64);

    __shared__ double ws[256 / 64];
    if ((tid & 63) == 0) ws[tid >> 6] = sum;
    __syncthreads();
    if (tid == 0) {
        double t = 0.0;
        #pragma unroll
        for (int w = 0; w < 256 / 64; ++w) t += ws[w];
        out[0] = (float)(t * scale);
    }
}

extern "C" void kernel_launch(void* const* d_in, const int* in_sizes, int n_in,
                              void* d_out, int out_size, void* d_ws, size_t ws_size,
                              hipStream_t stream) {
    const float* points  = (const float*)d_in[0];
    const float* outputs = (const float*)d_in[1];
    float* out = (float*)d_out;

    const int n = in_sizes[0] / 2;             // 8192
    double* partials = (double*)d_ws;          // 2064 * 8B = 16.5 KB scratch

    cont_pairs<<<dim3(NBLOCKS), dim3(256), 0, stream>>>(points, outputs, partials);

    // each unordered pair counted once -> weight 2 folded into the scale
    const double scale = 0.01 * 2.0 / ((double)n * (double)(n - 1));
    cont_final<<<1, 256, 0, stream>>>(partials, NBLOCKS, out, scale);
}